// Round 11
// baseline (389.703 us; speedup 1.0000x reference)
//
#include <hip/hip_runtime.h>
#include <hip/hip_bf16.h>
#include <cstdint>

#define B_    256
#define N_    343
#define C_    192
#define H_    6
#define D_    32
#define NW_   64
#define M_    (B_*N_)           // 87808 = 343*256
#define NN_   (N_*N_)           // 117649
#define VTS_  352               // v-transposed row stride (m padded to 22*16)
#define VLS_  360               // V LDS row stride (elems): 720B, 16B-aligned, 4-way banks
#define RPG_  86                // rpbt m-groups (ceil(343/4)); groups>=86 are all-masked pad
#define SCALE_ 0.17677669529663687f   // 32^-0.5
#define LOG2E_ 1.4426950408889634f
#define SCALE_LOG2E_ (SCALE_ * LOG2E_)

typedef unsigned short ushort_t;
typedef __attribute__((ext_vector_type(8))) short short8;   // 8 bf16 = MFMA A/B frag
typedef __attribute__((ext_vector_type(4))) float f32x4;    // 16x16 MFMA C/D frag
typedef __attribute__((ext_vector_type(16))) float f32x16;  // 32x32 MFMA C/D frag

__device__ __forceinline__ float b2f(unsigned int u) {
    return __uint_as_float(u << 16);
}
__device__ __forceinline__ unsigned int f2b(float f) {
    unsigned int x = __float_as_uint(f);
    x += 0x7FFFu + ((x >> 16) & 1u);   // RNE
    return x >> 16;
}
// packed 2xbf16 (RNE) in one instruction: lo=a, hi=b
__device__ __forceinline__ unsigned int cvt_pk(float a, float b) {
    unsigned int r;
    asm("v_cvt_pk_bf16_f32 %0, %1, %2" : "=v"(r) : "v"(a), "v"(b));
    return r;
}
// v_permlane32_swap_b32: x'[0:31]=x[0:31], x'[32:63]=y[0:31];
//                        y'[0:31]=x[32:63], y'[32:63]=y[32:63]
__device__ __forceinline__ void pswap(unsigned int &x, unsigned int &y) {
    asm("v_permlane32_swap_b32 %0, %1" : "+v"(x), "+v"(y));
}

// ---------------------------------------------------------------------------
// Convert all weight matrices fp32 -> bf16 once: wb = [q_w | k_w | v_w | proj_w]
// each 192x192 natural row-major.
// ---------------------------------------------------------------------------
__global__ __launch_bounds__(256) void wcvt(
    const float* __restrict__ qw, const float* __restrict__ kvw,
    const float* __restrict__ pw, ushort_t* __restrict__ wb)
{
    int i = blockIdx.x * 256 + threadIdx.x;   // float4 chunk index, 36864 total
    if (i >= 36864) return;
    float4 v;
    if (i < 9216)       v = ((const float4*)qw)[i];
    else if (i < 27648) v = ((const float4*)kvw)[i - 9216];   // k then v slices of kv_w
    else                v = ((const float4*)pw)[i - 27648];
    uint2 u;
    u.x = cvt_pk(v.x, v.y);
    u.y = cvt_pk(v.z, v.w);
    ((uint2*)wb)[i] = u;
}

// ---------------------------------------------------------------------------
// QKV projection, bf16 MFMA — exact-fit grid (R10 structure, unchanged this
// round to isolate the attn change). 512 blocks = 2/CU resident; each block
// owns 2-3 jobs = (256-row m-group, jsel); job = mgrp*3+jsel so consecutive
// jobs share x rows in L2. Waves own 32 rows: one LDS wf read feeds 2 MFMAs.
// jsel 0/1: 8B packed stores to [bh][n][d]. jsel 2: vtb[bh][d][n], lanes =
// consecutive n -> coalesced 32B runs.
// ---------------------------------------------------------------------------
__global__ __launch_bounds__(512, 2) void gemm_qkv(
    const float* __restrict__ xq, const float* __restrict__ xkv,
    const ushort_t* __restrict__ wb,
    const float* __restrict__ qbias, const float* __restrict__ kvbias,
    ushort_t* __restrict__ qx, ushort_t* __restrict__ kx,
    ushort_t* __restrict__ vtb)
{
    __shared__ ushort_t wls[192 * 200];   // 76800 B, stride 200 -> 2-way banks
    __shared__ float    bls[192];         // bias for current jsel

    const int t = threadIdx.x, wv = t >> 6, lane = t & 63;
    const int quad = lane >> 4, col = lane & 15;
    // XCD chunk: 512 = 8 * 64 -> consecutive logical blocks share an XCD L2
    const int lbid = (blockIdx.x & 7) * 64 + (blockIdx.x >> 3);
    // 1029 jobs = 512*2 + 5: first 5 logical blocks take 3
    const int start = lbid * 2 + (lbid < 5 ? lbid : 5);
    const int cnt = 2 + (lbid < 5 ? 1 : 0);

    for (int ji = 0; ji < cnt; ++ji) {
        const int job = start + ji;
        const int mgrp = job / 3, jsel = job - mgrp * 3;
        const int m0 = mgrp * 256;
        const float* Xf = (jsel == 0) ? xq : xkv;
        const float* bias = (jsel == 0) ? qbias : (jsel == 1 ? kvbias : kvbias + 192);
        const float alpha = (jsel == 0) ? SCALE_LOG2E_ : 1.0f;   // q carries scale*log2e

        // stage W + bias for this jsel (L2-resident). jsel changes every job.
        if (ji) __syncthreads();                 // readers of old W done
        {
            const ushort_t* W = wb + (size_t)jsel * 36864;
            for (int c = t; c < 4608; c += 512) {
                int row = c / 24, off = (c % 24) * 8;
                *(short8*)(wls + row * 200 + off) = *(const short8*)(W + row * 192 + off);
            }
            if (t < 48) ((float4*)bls)[t] = ((const float4*)bias)[t];
        }

        // X: 2 subtiles (rows wv*32+sub*16+col), 6 kt, fp32 -> bf16 in regs
        short8 xf[2][6];
        #pragma unroll
        for (int sub = 0; sub < 2; ++sub) {
            const float* xp = Xf + (size_t)(m0 + wv * 32 + sub * 16 + col) * 192;
            float4 a0[6], a1[6];
            #pragma unroll
            for (int kt = 0; kt < 6; ++kt) {
                a0[kt] = *(const float4*)(xp + kt * 32 + quad * 8);
                a1[kt] = *(const float4*)(xp + kt * 32 + quad * 8 + 4);
            }
            #pragma unroll
            for (int kt = 0; kt < 6; ++kt) {
                union { short8 s; unsigned int u[4]; } f;
                f.u[0] = cvt_pk(a0[kt].x, a0[kt].y);
                f.u[1] = cvt_pk(a0[kt].z, a0[kt].w);
                f.u[2] = cvt_pk(a1[kt].x, a1[kt].y);
                f.u[3] = cvt_pk(a1[kt].z, a1[kt].w);
                xf[sub][kt] = f.s;
            }
        }
        __syncthreads();   // W staged before reads

        f32x4 acc[2][12] = {};
        #pragma unroll
        for (int kt = 0; kt < 6; ++kt)
            #pragma unroll
            for (int ct = 0; ct < 12; ++ct) {
                short8 wf = *(const short8*)(wls + (ct * 16 + col) * 200 + kt * 32 + quad * 8);
                acc[0][ct] = __builtin_amdgcn_mfma_f32_16x16x32_bf16(wf, xf[0][kt], acc[0][ct], 0, 0, 0);
                acc[1][ct] = __builtin_amdgcn_mfma_f32_16x16x32_bf16(wf, xf[1][kt], acc[1][ct], 0, 0, 0);
            }

        if (jsel < 2) {
            // epilogue ^T: D[row=j-sub][col=token]; pack 4 d -> 8B store
            ushort_t* o16 = (jsel == 0) ? qx : kx;
            #pragma unroll
            for (int sub = 0; sub < 2; ++sub) {
                int m = m0 + wv * 32 + sub * 16 + col;
                int bb = m / N_, nn = m - bb * N_;
                #pragma unroll
                for (int ct = 0; ct < 12; ++ct) {
                    float4 bv = *(const float4*)(bls + ct * 16 + quad * 4);
                    int hh = ct >> 1;
                    int dbase = (ct & 1) * 16 + quad * 4;
                    float v0 = (acc[sub][ct][0] + bv.x) * alpha;
                    float v1 = (acc[sub][ct][1] + bv.y) * alpha;
                    float v2 = (acc[sub][ct][2] + bv.z) * alpha;
                    float v3 = (acc[sub][ct][3] + bv.w) * alpha;
                    uint2 pk;
                    pk.x = cvt_pk(v0, v1);
                    pk.y = cvt_pk(v2, v3);
                    *(uint2*)(o16 + (((size_t)bb * H_ + hh) * N_ + nn) * D_ + dbase) = pk;
                }
            }
        } else {
            // epilogue V^T: vtb[bh][d][n]; lanes = consecutive n -> coalesced
            #pragma unroll
            for (int sub = 0; sub < 2; ++sub) {
                int m = m0 + wv * 32 + sub * 16 + col;
                int bb = m / N_, nn = m - bb * N_;
                #pragma unroll
                for (int ct = 0; ct < 12; ++ct) {
                    float4 bv = *(const float4*)(bls + ct * 16 + quad * 4);
                    int hh = ct >> 1;
                    int d0 = (ct & 1) * 16 + quad * 4;
                    unsigned int u01 = cvt_pk(acc[sub][ct][0] + bv.x, acc[sub][ct][1] + bv.y);
                    unsigned int u23 = cvt_pk(acc[sub][ct][2] + bv.z, acc[sub][ct][3] + bv.w);
                    ushort_t* vp = vtb + (((size_t)bb * H_ + hh) * D_ + d0) * VTS_ + nn;
                    vp[0]            = (ushort_t)u01;
                    vp[VTS_]         = (ushort_t)(u01 >> 16);
                    vp[2 * VTS_]     = (ushort_t)u23;
                    vp[3 * VTS_]     = (ushort_t)(u23 >> 16);
                }
            }
        }
    }
}

// ---------------------------------------------------------------------------
// Output projection: aob bf16 [m][192] @ proj_w^T + bias -> fp32 out [m][192].
// 343 blocks x 256-row tiles, waves own 32 rows (R10 structure, unchanged).
// ---------------------------------------------------------------------------
__global__ __launch_bounds__(512, 2) void gemm_out(
    const ushort_t* __restrict__ aob, const ushort_t* __restrict__ wb,
    const float* __restrict__ pbias, float* __restrict__ out)
{
    __shared__ ushort_t wls[192 * 200];

    const int t = threadIdx.x, wv = t >> 6, lane = t & 63;
    const int quad = lane >> 4, col = lane & 15;
    const int m0 = blockIdx.x * 256;
    const ushort_t* W = wb + (size_t)3 * 36864;

    // x (aob) loads first (already bf16), then W staging
    short8 xf[2][6];
    #pragma unroll
    for (int sub = 0; sub < 2; ++sub) {
        const ushort_t* xp = aob + (size_t)(m0 + wv * 32 + sub * 16 + col) * 192;
        #pragma unroll
        for (int kt = 0; kt < 6; ++kt)
            xf[sub][kt] = *(const short8*)(xp + kt * 32 + quad * 8);
    }
    for (int c = t; c < 4608; c += 512) {
        int row = c / 24, off = (c % 24) * 8;
        *(short8*)(wls + row * 200 + off) = *(const short8*)(W + row * 192 + off);
    }
    __syncthreads();

    f32x4 acc[2][12] = {};
    #pragma unroll
    for (int kt = 0; kt < 6; ++kt)
        #pragma unroll
        for (int ct = 0; ct < 12; ++ct) {
            short8 wf = *(const short8*)(wls + (ct * 16 + col) * 200 + kt * 32 + quad * 8);
            acc[0][ct] = __builtin_amdgcn_mfma_f32_16x16x32_bf16(wf, xf[0][kt], acc[0][ct], 0, 0, 0);
            acc[1][ct] = __builtin_amdgcn_mfma_f32_16x16x32_bf16(wf, xf[1][kt], acc[1][ct], 0, 0, 0);
        }

    #pragma unroll
    for (int sub = 0; sub < 2; ++sub) {
        int m = m0 + wv * 32 + sub * 16 + col;
        #pragma unroll
        for (int ct = 0; ct < 12; ++ct) {
            float4 bv = *(const float4*)(pbias + ct * 16 + quad * 4);
            float4 vo;
            vo.x = acc[sub][ct][0] + bv.x; vo.y = acc[sub][ct][1] + bv.y;
            vo.z = acc[sub][ct][2] + bv.z; vo.w = acc[sub][ct][3] + bv.w;
            *(float4*)(out + (size_t)m * 192 + ct * 16 + quad * 4) = vo;
        }
    }
}

// ---------------------------------------------------------------------------
// rpbt[h][mg=m>>2][n] = uint2 of 4 bf16 (m-group), pre-scaled by log2e.
// In attn, lane = n -> 8B uint2 load at (h*RPG_+mg)*N_+n is lane-coalesced.
// ---------------------------------------------------------------------------
__global__ __launch_bounds__(256) void rpb_gather_b(
    const float* __restrict__ table, const int* __restrict__ rpi,
    ushort_t* __restrict__ rpbt)
{
    int n = blockIdx.x;
    for (int m = threadIdx.x; m < N_; m += 256) {
        int id = rpi[n * N_ + m];
        int mg = m >> 2, mi = m & 3;
        #pragma unroll
        for (int h = 0; h < H_; ++h)
            rpbt[((((size_t)h * RPG_ + mg) * N_) + n) * 4 + mi] =
                (ushort_t)f2b(table[(size_t)id * H_ + h] * LOG2E_);
    }
}

// ---------------------------------------------------------------------------
// mbt[w][dw=m>>5][n]: bit (m&31) set iff mask[w][n][m]==0. In attn, lane = n
// -> scalar u32 load at (w*12+dw)*N_+n is lane-coalesced.
// ---------------------------------------------------------------------------
__global__ __launch_bounds__(256) void mask_bits(
    const float* __restrict__ mask, unsigned int* __restrict__ mbt)
{
    int gw   = blockIdx.x * 4 + (threadIdx.x >> 6);
    int lane = threadIdx.x & 63;
    int n = gw % N_, w = gw / N_;
    if (w >= NW_) return;
    const float* mrow = mask + ((size_t)w * N_ + n) * N_;
    #pragma unroll
    for (int seg = 0; seg < 6; ++seg) {
        int m = seg * 64 + lane;
        float v = (m < N_) ? mrow[m] : -100.f;
        unsigned long long bm = __ballot(v > -50.f);
        if (lane < 2)
            mbt[((size_t)w * 12 + seg * 2 + lane) * N_ + n] =
                (unsigned int)(bm >> (lane * 32));
    }
}

// zero vtb pad columns n in [343,352)
__global__ __launch_bounds__(256) void vt_pad(ushort_t* __restrict__ vtb)
{
    int bh = blockIdx.x;
    for (int i = threadIdx.x; i < D_ * (VTS_ - N_); i += 256) {
        int d = i / (VTS_ - N_), m = N_ + i % (VTS_ - N_);
        vtb[((size_t)bh * D_ + d) * VTS_ + m] = 0;
    }
}

// ---------------------------------------------------------------------------
// Streaming MFMA attention — VALU-trim round (R11). R10 showed VALUBusy 85%:
// attn is VALU-issue-bound. Cuts per 32-key chunk:
//  * rpb+mask now enter via the MFMA C-operand (C_in = masked ? -3e38 : rpb):
//    kills 16 zero-init movs AND 16 bias adds; exp2 applies directly to s;
//    masked entries exit MFMA at -3e38 -> exp2 -> exact 0 (same result).
//    Requires K pad rows 343..351 zeroed (NaN guard) — 720B LDS memset.
//  * mg clamp specialized: only (kt=10,g=3) can exceed RPG_-1, and those m
//    are all masked -> compile-time -3e38, no load, no runtime clamp.
//  * hh folded into rpb base pointer -> compile-time indices, no 64b muls.
//  * V staging division-free (fixed row per thread).
// LDS = ks 28160 + vls 23040 = 51200B -> 3 blocks/CU.
// Grid: 1-D 4608 = 3 qt x 1536 bh, XCD-chunked (576/XCD) for K/V L2 reuse.
// ---------------------------------------------------------------------------
__global__ __launch_bounds__(256, 3) void attn_mfma(
    const ushort_t* __restrict__ qb, const ushort_t* __restrict__ kb,
    const ushort_t* __restrict__ vtb, const ushort_t* __restrict__ rpbt,
    const unsigned int* __restrict__ mbt, ushort_t* __restrict__ aob)
{
    __shared__ ushort_t ks[352 * 40];    // 28160 B
    __shared__ ushort_t vls[32 * VLS_];  // 23040 B

    const int t = threadIdx.x, wv = t >> 6, lane = t & 63;
    const int hh = lane >> 5, c = lane & 31;     // half, col (= q-row / d-row)
    // XCD-chunked 1-D grid: 4608 = 8 * 576; logical order (b, h, qt) qt-fastest
    const int lid = blockIdx.x;
    const int wg = (lid & 7) * 576 + (lid >> 3);
    const int qt = wg % 3;
    const int bhx = wg / 3;
    const int h = bhx % H_, b = bhx / H_;
    const int bh = b * H_ + h;
    const int w  = b & (NW_ - 1);
    const int n0 = qt * 128 + wv * 32;

    // stage K tile [m][d], row stride 40 elems
    const ushort_t* kbase = kb + (size_t)bh * (N_ * D_);
    for (int cc = t; cc < (N_ * D_) / 8; cc += 256) {
        int row = cc >> 2, off = (cc & 3) * 8;
        *(short8*)(ks + row * 40 + off) = *(const short8*)(kbase + cc * 8);
    }
    // zero K pad rows 343..351 (contiguous [13720,14080)): C-in path needs
    // pad products finite (NaN + -3e38 = NaN would poison exp2)
    for (int cc = t; cc < 360; cc += 256) ks[13720 + cc] = 0;

    // stage V^T tile [d][m], row stride VLS_; division-free: thread owns row
    // vd = t>>3, walks 44 16B chunks 8 threads wide. Pad cols zeroed (vt_pad).
    {
        const int vd = t >> 3, vj0 = t & 7;
        const ushort_t* vsrc = vtb + (size_t)bh * (D_ * VTS_) + (size_t)vd * VTS_;
        ushort_t* vdst = vls + vd * VLS_;
        #pragma unroll
        for (int j = 0; j < 6; ++j) {
            int jj = vj0 + j * 8;
            if (jj < 44)
                *(short8*)(vdst + jj * 8) = *(const short8*)(vsrc + jj * 8);
        }
    }

    int nn = n0 + c; if (nn > N_ - 1) nn = N_ - 1;   // tail clamp (stores gated)
    // Q^T B-frags: lane (h,c): q[n=nn][d = h*8+j] and [16+h*8+j]
    const ushort_t* qp = qb + ((size_t)bh * N_ + nn) * D_;
    short8 qf0 = *(const short8*)(qp + hh * 8);
    short8 qf1 = *(const short8*)(qp + 16 + hh * 8);

    // mask dwords, lane-coalesced (transposed layout)
    unsigned int dwv[12];
    {
        const unsigned int* mbp = mbt + (size_t)w * 12 * N_ + nn;
        #pragma unroll
        for (int i = 0; i < 12; ++i) dwv[i] = mbp[i * N_];
    }
    // rpb uint2 (4 bf16) base for this (h, n, hh): index is compile-time per
    // unrolled (kt,g) -> no runtime 64b muls
    const uint2* rp2h = (const uint2*)rpbt + (size_t)h * (RPG_ * N_) + nn
                        + (size_t)hh * N_;

    __syncthreads();

    f32x16 oacc = {};
    float sum = 0.f;

    #pragma unroll
    for (int kt = 0; kt < 11; ++kt) {
        // QK^T: A = K rows (lane c = key m), k = d
        const ushort_t* krow = ks + (kt * 32 + c) * 40 + hh * 8;
        short8 ka  = *(const short8*)(krow);        // d = h*8 + j
        short8 kb2 = *(const short8*)(krow + 16);   // d = 16 + h*8 + j
        // C-in = rpb (log2-domain) or -3e38 where masked; replaces zero-init,
        // bias-add and post-exp2 cndmask. reg 4g+i -> m = kt*32+8g+4hh+i.
        unsigned int nibs = dwv[kt] >> (hh * 4);
        f32x16 s;
        #pragma unroll
        for (int g = 0; g < 4; ++g) {
            if (kt == 10 && g == 3) {          // m >= 344: all masked, no load
                s[12] = -3.0e38f; s[13] = -3.0e38f;
                s[14] = -3.0e38f; s[15] = -3.0e38f;
            } else {
                uint2 rv = rp2h[(kt * 8 + 2 * g) * (size_t)N_];
                unsigned int nib = (nibs >> (g * 8)) & 0xFu;
                s[4*g+0] = (nib & 1u) ? b2f(rv.x & 0xffffu) : -3.0e38f;
                s[4*g+1] = (nib & 2u) ? b2f(rv.x >> 16)     : -3.0e38f;
                s[4*g+2] = (nib & 4u) ? b2f(rv.y & 0xffffu) : -3.0e38f;
                s[4*g+3] = (nib & 8u) ? b2f(rv.y >> 16)     : -3.0e38f;
            }
        }
        s = __builtin_amdgcn_mfma_f32_32x32x16_bf16(ka,  qf0, s, 0, 0, 0);
        s = __builtin_amdgcn_mfma_f32_32x32x16_bf16(kb2, qf1, s, 0, 0, 0);

        // exp2 + sum + pack (masked lanes: exp2(-3e38) = exact 0)
        unsigned int pk[8];
        #pragma unroll
        for (int g = 0; g < 4; ++g) {
            float e0 = __builtin_exp2f(s[4*g+0]);
            float e1 = __builtin_exp2f(s[4*g+1]);
            float e2 = __builtin_exp2f(s[4*g+2]);
            float e3 = __builtin_exp2f(s[4*g+3]);
            sum += (e0 + e1) + (e2 + e3);
            pk[2*g]   = cvt_pk(e0, e1);
            pk[2*g+1] = cvt_pk(e2, e3);
        }
        // D-layout -> B-operand layout via half-wave swaps
        pswap(pk[0], pk[2]);
        pswap(pk[1], pk[3]);
        pswap(pk[4], pk[6]);
        pswap(pk[5], pk[7]);
        union { short8 s8; unsigned int u[4]; } pf1, pf2;
        pf1.u[0] = pk[0]; pf1.u[1] = pk[1]; pf1.u[2] = pk[2]; pf1.u[3] = pk[3];
        pf2.u[0] = pk[4]; pf2.u[1] = pk[5]; pf2.u[2] = pk[6]; pf2.u[3] = pk[7];

        // PV: A = V^T rows from LDS (lane c = d), k = m-offset
        const ushort_t* vrow = vls + c * VLS_ + kt * 32 + hh * 8;
        short8 vf1 = *(const short8*)(vrow);
        short8 vf2 = *(const short8*)(vrow + 16);
        oacc = __builtin_amdgcn_mfma_f32_32x32x16_bf16(vf1, pf1.s8, oacc, 0, 0, 0);
        oacc = __builtin_amdgcn_mfma_f32_32x32x16_bf16(vf2, pf2.s8, oacc, 0, 0, 0);
    }

    sum += __shfl_xor(sum, 32);   // halves hold complementary m-subsets

    // store O^T: reg 4g+i -> d = 8g + 4h + i; 4x 8B packed stores
    int n = n0 + c;
    if (n < N_) {
        float inv = 1.0f / sum;
        ushort_t* op = aob + ((size_t)b * N_ + n) * C_ + h * D_ + hh * 4;
        #pragma unroll
        for (int g = 0; g < 4; ++g) {
            uint2 pkk;
            pkk.x = cvt_pk(oacc[4*g+0] * inv, oacc[4*g+1] * inv);
            pkk.y = cvt_pk(oacc[4*g+2] * inv, oacc[4*g+3] * inv);
            *(uint2*)(op + g * 8) = pkk;
        }
    }
}

// ---------------------------------------------------------------------------
extern "C" void kernel_launch(void* const* d_in, const int* in_sizes, int n_in,
                              void* d_out, int out_size, void* d_ws, size_t ws_size,
                              hipStream_t stream)
{
    const float* x_q    = (const float*)d_in[0];
    const float* x_kv   = (const float*)d_in[1];
    const float* mask   = (const float*)d_in[2];
    const float* q_w    = (const float*)d_in[3];
    const float* q_b    = (const float*)d_in[4];
    const float* kv_w   = (const float*)d_in[5];
    const float* kv_b   = (const float*)d_in[6];
    const float* proj_w = (const float*)d_in[7];
    const float* proj_b = (const float*)d_in[8];
    const float* rpb_t  = (const float*)d_in[9];
    const int*   rpi    = (const int*)d_in[10];
    float* out = (float*)d_out;

    // ws: qx 33.7 | kx 33.7 | vtb 34.6 | aob 33.7 | rpbt 1.42 | wb 0.29 | mbt 1.05 MB
    // total 138,522,336 B == round-4 high-water mark (no growth)
    const size_t QKV  = (size_t)B_ * H_ * N_ * D_;       // 16,859,136
    const size_t QKV2 = (size_t)B_ * H_ * D_ * VTS_;     // 17,301,504
    char* ws = (char*)d_ws;
    ushort_t* qx   = (ushort_t*)ws;
    ushort_t* kx   = qx + QKV;
    ushort_t* vtb  = kx + QKV;
    ushort_t* aob  = vtb + QKV2;
    ushort_t* rpbt = aob + QKV;                          // 16B-aligned offset
    ushort_t* wb   = rpbt + (size_t)H_ * RPG_ * N_ * 4;  // 707,952 elems
    unsigned int* mbt = (unsigned int*)(wb + 147456);

    wcvt<<<144, 256, 0, stream>>>(q_w, kv_w, proj_w, wb);
    rpb_gather_b<<<N_, 256, 0, stream>>>(rpb_t, rpi, rpbt);
    mask_bits<<<(NW_ * N_) / 4, 256, 0, stream>>>(mask, mbt);
    vt_pad<<<B_ * H_, 256, 0, stream>>>(vtb);
    gemm_qkv<<<512, 512, 0, stream>>>(
        x_q, x_kv, wb, q_b, kv_b, qx, kx, vtb);
    attn_mfma<<<4608, 256, 0, stream>>>(qx, kx, vtb, rpbt, mbt, aob);
    gemm_out<<<343, 512, 0, stream>>>(aob, wb, proj_b, out);
}

// Round 12
// 371.757 us; speedup vs baseline: 1.0483x; 1.0483x over previous
//
#include <hip/hip_runtime.h>
#include <hip/hip_bf16.h>
#include <cstdint>

#define B_    256
#define N_    343
#define C_    192
#define H_    6
#define D_    32
#define NW_   64
#define M_    (B_*N_)           // 87808 = 343*256
#define NN_   (N_*N_)           // 117649
#define VTS_  352               // v-transposed row stride (m padded to 22*16)
#define VLS_  360               // V LDS row stride (elems): 720B, 16B-aligned, 4-way banks
#define RPG_  86                // rpbt m-groups (ceil(343/4)); groups>=86 are all-masked pad
#define NJOB_ 1029              // gemm_qkv jobs: 343 m-groups x 3 jsel
#define SCALE_ 0.17677669529663687f   // 32^-0.5
#define LOG2E_ 1.4426950408889634f
#define SCALE_LOG2E_ (SCALE_ * LOG2E_)

typedef unsigned short ushort_t;
typedef __attribute__((ext_vector_type(8))) short short8;   // 8 bf16 = MFMA A/B frag
typedef __attribute__((ext_vector_type(4))) float f32x4;    // 16x16 MFMA C/D frag
typedef __attribute__((ext_vector_type(16))) float f32x16;  // 32x32 MFMA C/D frag

__device__ __forceinline__ float b2f(unsigned int u) {
    return __uint_as_float(u << 16);
}
__device__ __forceinline__ unsigned int f2b(float f) {
    unsigned int x = __float_as_uint(f);
    x += 0x7FFFu + ((x >> 16) & 1u);   // RNE
    return x >> 16;
}
// packed 2xbf16 (RNE) in one instruction: lo=a, hi=b
__device__ __forceinline__ unsigned int cvt_pk(float a, float b) {
    unsigned int r;
    asm("v_cvt_pk_bf16_f32 %0, %1, %2" : "=v"(r) : "v"(a), "v"(b));
    return r;
}
// v_permlane32_swap_b32: x'[0:31]=x[0:31], x'[32:63]=y[0:31];
//                        y'[0:31]=x[32:63], y'[32:63]=y[32:63]
__device__ __forceinline__ void pswap(unsigned int &x, unsigned int &y) {
    asm("v_permlane32_swap_b32 %0, %1" : "+v"(x), "+v"(y));
}

// ---------------------------------------------------------------------------
// Convert all weight matrices fp32 -> bf16 once: wb = [q_w | k_w | v_w | proj_w]
// each 192x192 natural row-major. Also zeroes the gemm_qkv job counter
// (parked in aob[0] — dead storage until attn overwrites it).
// ---------------------------------------------------------------------------
__global__ __launch_bounds__(256) void wcvt(
    const float* __restrict__ qw, const float* __restrict__ kvw,
    const float* __restrict__ pw, ushort_t* __restrict__ wb,
    unsigned int* __restrict__ ctr)
{
    int i = blockIdx.x * 256 + threadIdx.x;   // float4 chunk index, 36864 total
    if (i == 0) *ctr = 0;
    if (i >= 36864) return;
    float4 v;
    if (i < 9216)       v = ((const float4*)qw)[i];
    else if (i < 27648) v = ((const float4*)kvw)[i - 9216];   // k then v slices of kv_w
    else                v = ((const float4*)pw)[i - 27648];
    uint2 u;
    u.x = cvt_pk(v.x, v.y);
    u.y = cvt_pk(v.z, v.w);
    ((uint2*)wb)[i] = u;
}

// ---------------------------------------------------------------------------
// QKV projection, bf16 MFMA — WORK-STEALING (round 12).
// Evidence: R10's Occupancy 17.9% vs 50% resident ceiling = time-averaged
// idle tail (5 blocks carry 3 jobs vs 2 -> last ~1/3 of the kernel runs on
// 5/256 CUs). R8/R9/R10 (110/105/101us) all fit {work x rounds + tail}.
// Fix: 512 persistent blocks pull (mgrp,jsel) jobs from a global atomic
// counter -> perfect balance, no tail. Body per job identical to R10:
// 256-row m-group, waves own 32 rows (1 wf read feeds 2 MFMAs), W+bias
// staged per job from L2.
// jsel 0/1: 8B packed stores to [bh][n][d]. jsel 2: vtb[bh][d][n], lanes =
// consecutive n -> coalesced 32B runs.
// ---------------------------------------------------------------------------
__global__ __launch_bounds__(512, 2) void gemm_qkv(
    const float* __restrict__ xq, const float* __restrict__ xkv,
    const ushort_t* __restrict__ wb,
    const float* __restrict__ qbias, const float* __restrict__ kvbias,
    ushort_t* __restrict__ qx, ushort_t* __restrict__ kx,
    ushort_t* __restrict__ vtb, unsigned int* __restrict__ ctr)
{
    __shared__ ushort_t wls[192 * 200];   // 76800 B, stride 200 -> 2-way banks
    __shared__ float    bls[192];         // bias for current jsel
    __shared__ int      sjob;

    const int t = threadIdx.x, wv = t >> 6, lane = t & 63;
    const int quad = lane >> 4, col = lane & 15;

    for (;;) {
        __syncthreads();                  // prev W readers done; sjob reusable
        if (t == 0) sjob = (int)atomicAdd(ctr, 1u);
        __syncthreads();
        const int job = sjob;
        if (job >= NJOB_) break;          // uniform exit (sjob same for all)

        const int mgrp = job / 3, jsel = job - mgrp * 3;
        const int m0 = mgrp * 256;
        const float* Xf = (jsel == 0) ? xq : xkv;
        const float* bias = (jsel == 0) ? qbias : (jsel == 1 ? kvbias : kvbias + 192);
        const float alpha = (jsel == 0) ? SCALE_LOG2E_ : 1.0f;   // q carries scale*log2e

        // stage W + bias for this jsel (L2-resident)
        {
            const ushort_t* W = wb + (size_t)jsel * 36864;
            for (int c = t; c < 4608; c += 512) {
                int row = c / 24, off = (c % 24) * 8;
                *(short8*)(wls + row * 200 + off) = *(const short8*)(W + row * 192 + off);
            }
            if (t < 48) ((float4*)bls)[t] = ((const float4*)bias)[t];
        }

        // X: 2 subtiles (rows wv*32+sub*16+col), 6 kt, fp32 -> bf16 in regs
        short8 xf[2][6];
        #pragma unroll
        for (int sub = 0; sub < 2; ++sub) {
            const float* xp = Xf + (size_t)(m0 + wv * 32 + sub * 16 + col) * 192;
            float4 a0[6], a1[6];
            #pragma unroll
            for (int kt = 0; kt < 6; ++kt) {
                a0[kt] = *(const float4*)(xp + kt * 32 + quad * 8);
                a1[kt] = *(const float4*)(xp + kt * 32 + quad * 8 + 4);
            }
            #pragma unroll
            for (int kt = 0; kt < 6; ++kt) {
                union { short8 s; unsigned int u[4]; } f;
                f.u[0] = cvt_pk(a0[kt].x, a0[kt].y);
                f.u[1] = cvt_pk(a0[kt].z, a0[kt].w);
                f.u[2] = cvt_pk(a1[kt].x, a1[kt].y);
                f.u[3] = cvt_pk(a1[kt].z, a1[kt].w);
                xf[sub][kt] = f.s;
            }
        }
        __syncthreads();   // W staged before reads

        f32x4 acc[2][12] = {};
        #pragma unroll
        for (int kt = 0; kt < 6; ++kt)
            #pragma unroll
            for (int ct = 0; ct < 12; ++ct) {
                short8 wf = *(const short8*)(wls + (ct * 16 + col) * 200 + kt * 32 + quad * 8);
                acc[0][ct] = __builtin_amdgcn_mfma_f32_16x16x32_bf16(wf, xf[0][kt], acc[0][ct], 0, 0, 0);
                acc[1][ct] = __builtin_amdgcn_mfma_f32_16x16x32_bf16(wf, xf[1][kt], acc[1][ct], 0, 0, 0);
            }

        if (jsel < 2) {
            // epilogue ^T: D[row=j-sub][col=token]; pack 4 d -> 8B store
            ushort_t* o16 = (jsel == 0) ? qx : kx;
            #pragma unroll
            for (int sub = 0; sub < 2; ++sub) {
                int m = m0 + wv * 32 + sub * 16 + col;
                int bb = m / N_, nn = m - bb * N_;
                #pragma unroll
                for (int ct = 0; ct < 12; ++ct) {
                    float4 bv = *(const float4*)(bls + ct * 16 + quad * 4);
                    int hh = ct >> 1;
                    int dbase = (ct & 1) * 16 + quad * 4;
                    float v0 = (acc[sub][ct][0] + bv.x) * alpha;
                    float v1 = (acc[sub][ct][1] + bv.y) * alpha;
                    float v2 = (acc[sub][ct][2] + bv.z) * alpha;
                    float v3 = (acc[sub][ct][3] + bv.w) * alpha;
                    uint2 pk;
                    pk.x = cvt_pk(v0, v1);
                    pk.y = cvt_pk(v2, v3);
                    *(uint2*)(o16 + (((size_t)bb * H_ + hh) * N_ + nn) * D_ + dbase) = pk;
                }
            }
        } else {
            // epilogue V^T: vtb[bh][d][n]; lanes = consecutive n -> coalesced
            #pragma unroll
            for (int sub = 0; sub < 2; ++sub) {
                int m = m0 + wv * 32 + sub * 16 + col;
                int bb = m / N_, nn = m - bb * N_;
                #pragma unroll
                for (int ct = 0; ct < 12; ++ct) {
                    float4 bv = *(const float4*)(bls + ct * 16 + quad * 4);
                    int hh = ct >> 1;
                    int d0 = (ct & 1) * 16 + quad * 4;
                    unsigned int u01 = cvt_pk(acc[sub][ct][0] + bv.x, acc[sub][ct][1] + bv.y);
                    unsigned int u23 = cvt_pk(acc[sub][ct][2] + bv.z, acc[sub][ct][3] + bv.w);
                    ushort_t* vp = vtb + (((size_t)bb * H_ + hh) * D_ + d0) * VTS_ + nn;
                    vp[0]            = (ushort_t)u01;
                    vp[VTS_]         = (ushort_t)(u01 >> 16);
                    vp[2 * VTS_]     = (ushort_t)u23;
                    vp[3 * VTS_]     = (ushort_t)(u23 >> 16);
                }
            }
        }
    }
}

// ---------------------------------------------------------------------------
// Output projection: aob bf16 [m][192] @ proj_w^T + bias -> fp32 out [m][192].
// 343 blocks x 256-row tiles, waves own 32 rows (unchanged this round).
// ---------------------------------------------------------------------------
__global__ __launch_bounds__(512, 2) void gemm_out(
    const ushort_t* __restrict__ aob, const ushort_t* __restrict__ wb,
    const float* __restrict__ pbias, float* __restrict__ out)
{
    __shared__ ushort_t wls[192 * 200];

    const int t = threadIdx.x, wv = t >> 6, lane = t & 63;
    const int quad = lane >> 4, col = lane & 15;
    const int m0 = blockIdx.x * 256;
    const ushort_t* W = wb + (size_t)3 * 36864;

    // x (aob) loads first (already bf16), then W staging
    short8 xf[2][6];
    #pragma unroll
    for (int sub = 0; sub < 2; ++sub) {
        const ushort_t* xp = aob + (size_t)(m0 + wv * 32 + sub * 16 + col) * 192;
        #pragma unroll
        for (int kt = 0; kt < 6; ++kt)
            xf[sub][kt] = *(const short8*)(xp + kt * 32 + quad * 8);
    }
    for (int c = t; c < 4608; c += 512) {
        int row = c / 24, off = (c % 24) * 8;
        *(short8*)(wls + row * 200 + off) = *(const short8*)(W + row * 192 + off);
    }
    __syncthreads();

    f32x4 acc[2][12] = {};
    #pragma unroll
    for (int kt = 0; kt < 6; ++kt)
        #pragma unroll
        for (int ct = 0; ct < 12; ++ct) {
            short8 wf = *(const short8*)(wls + (ct * 16 + col) * 200 + kt * 32 + quad * 8);
            acc[0][ct] = __builtin_amdgcn_mfma_f32_16x16x32_bf16(wf, xf[0][kt], acc[0][ct], 0, 0, 0);
            acc[1][ct] = __builtin_amdgcn_mfma_f32_16x16x32_bf16(wf, xf[1][kt], acc[1][ct], 0, 0, 0);
        }

    #pragma unroll
    for (int sub = 0; sub < 2; ++sub) {
        int m = m0 + wv * 32 + sub * 16 + col;
        #pragma unroll
        for (int ct = 0; ct < 12; ++ct) {
            float4 bv = *(const float4*)(pbias + ct * 16 + quad * 4);
            float4 vo;
            vo.x = acc[sub][ct][0] + bv.x; vo.y = acc[sub][ct][1] + bv.y;
            vo.z = acc[sub][ct][2] + bv.z; vo.w = acc[sub][ct][3] + bv.w;
            *(float4*)(out + (size_t)m * 192 + ct * 16 + quad * 4) = vo;
        }
    }
}

// ---------------------------------------------------------------------------
// rpbt[h][mg=m>>2][n] = uint2 of 4 bf16 (m-group), pre-scaled by log2e.
// In attn, lane = n -> 8B uint2 load at (h*RPG_+mg)*N_+n is lane-coalesced.
// ---------------------------------------------------------------------------
__global__ __launch_bounds__(256) void rpb_gather_b(
    const float* __restrict__ table, const int* __restrict__ rpi,
    ushort_t* __restrict__ rpbt)
{
    int n = blockIdx.x;
    for (int m = threadIdx.x; m < N_; m += 256) {
        int id = rpi[n * N_ + m];
        int mg = m >> 2, mi = m & 3;
        #pragma unroll
        for (int h = 0; h < H_; ++h)
            rpbt[((((size_t)h * RPG_ + mg) * N_) + n) * 4 + mi] =
                (ushort_t)f2b(table[(size_t)id * H_ + h] * LOG2E_);
    }
}

// ---------------------------------------------------------------------------
// mbt[w][dw=m>>5][n]: bit (m&31) set iff mask[w][n][m]==0. In attn, lane = n
// -> scalar u32 load at (w*12+dw)*N_+n is lane-coalesced.
// ---------------------------------------------------------------------------
__global__ __launch_bounds__(256) void mask_bits(
    const float* __restrict__ mask, unsigned int* __restrict__ mbt)
{
    int gw   = blockIdx.x * 4 + (threadIdx.x >> 6);
    int lane = threadIdx.x & 63;
    int n = gw % N_, w = gw / N_;
    if (w >= NW_) return;
    const float* mrow = mask + ((size_t)w * N_ + n) * N_;
    #pragma unroll
    for (int seg = 0; seg < 6; ++seg) {
        int m = seg * 64 + lane;
        float v = (m < N_) ? mrow[m] : -100.f;
        unsigned long long bm = __ballot(v > -50.f);
        if (lane < 2)
            mbt[((size_t)w * 12 + seg * 2 + lane) * N_ + n] =
                (unsigned int)(bm >> (lane * 32));
    }
}

// zero vtb pad columns n in [343,352) (keeps PV V-operand pad finite)
__global__ __launch_bounds__(256) void vt_pad(ushort_t* __restrict__ vtb)
{
    int bh = blockIdx.x;
    for (int i = threadIdx.x; i < D_ * (VTS_ - N_); i += 256) {
        int d = i / (VTS_ - N_), m = N_ + i % (VTS_ - N_);
        vtb[((size_t)bh * D_ + d) * VTS_ + m] = 0;
    }
}

// ---------------------------------------------------------------------------
// Streaming MFMA attention — HIGH-OCCUPANCY round (R12). R11's falsifier:
// cutting VALU ops dropped VALUBusy 85->76% with dur unchanged -> attn is
// LATENCY-bound at 3 blocks/CU (30% occ), not VALU-bound. Fix: drop the K
// LDS stage entirely and read K from global. K's access is lane=row=m ->
// a wave's 2 b128 loads cover 2KB contiguous (perfectly coalesced) and
// L2-XCD-local (grid swizzle kept); LDS staging of K only bought 4x reuse
// at the cost of capping residency. LDS = V only (23040B) -> 7 blocks/CU,
// 28 waves (87% ceiling), __launch_bounds__(256,7) (VGPR<=73, was 68).
// K pad rows 343..351 read finite neighbor ws data; mask bits 0 -> C-in
// -3e38 -> exp2 -> 0 (all ws bytes are values we wrote -> no NaN).
// V stays in LDS: its lane=d access at 704B row stride is the R4 scatter
// disaster if read from global.
// ---------------------------------------------------------------------------
__global__ __launch_bounds__(256, 7) void attn_mfma(
    const ushort_t* __restrict__ qb, const ushort_t* __restrict__ kb,
    const ushort_t* __restrict__ vtb, const ushort_t* __restrict__ rpbt,
    const unsigned int* __restrict__ mbt, ushort_t* __restrict__ aob)
{
    __shared__ ushort_t vls[32 * VLS_];  // 23040 B (V^T only)

    const int t = threadIdx.x, wv = t >> 6, lane = t & 63;
    const int hh = lane >> 5, c = lane & 31;     // half, col (= q-row / d-row)
    // XCD-chunked 1-D grid: 4608 = 8 * 576; logical order (b, h, qt) qt-fastest
    const int lid = blockIdx.x;
    const int wg = (lid & 7) * 576 + (lid >> 3);
    const int qt = wg % 3;
    const int bhx = wg / 3;
    const int h = bhx % H_, b = bhx / H_;
    const int bh = b * H_ + h;
    const int w  = b & (NW_ - 1);
    const int n0 = qt * 128 + wv * 32;

    // stage V^T tile [d][m], row stride VLS_; division-free: thread owns row
    // vd = t>>3, walks 44 16B chunks 8 threads wide. Pad cols zeroed (vt_pad).
    {
        const int vd = t >> 3, vj0 = t & 7;
        const ushort_t* vsrc = vtb + (size_t)bh * (D_ * VTS_) + (size_t)vd * VTS_;
        ushort_t* vdst = vls + vd * VLS_;
        #pragma unroll
        for (int j = 0; j < 6; ++j) {
            int jj = vj0 + j * 8;
            if (jj < 44)
                *(short8*)(vdst + jj * 8) = *(const short8*)(vsrc + jj * 8);
        }
    }

    int nn = n0 + c; if (nn > N_ - 1) nn = N_ - 1;   // tail clamp (stores gated)
    // Q^T B-frags: lane (h,c): q[n=nn][d = h*8+j] and [16+h*8+j]
    const ushort_t* qp = qb + ((size_t)bh * N_ + nn) * D_;
    short8 qf0 = *(const short8*)(qp + hh * 8);
    short8 qf1 = *(const short8*)(qp + 16 + hh * 8);

    // mask dwords, lane-coalesced (transposed layout)
    unsigned int dwv[12];
    {
        const unsigned int* mbp = mbt + (size_t)w * 12 * N_ + nn;
        #pragma unroll
        for (int i = 0; i < 12; ++i) dwv[i] = mbp[i * N_];
    }
    // rpb uint2 (4 bf16) base for this (h, n, hh): compile-time indices
    const uint2* rp2h = (const uint2*)rpbt + (size_t)h * (RPG_ * N_) + nn
                        + (size_t)hh * N_;
    // K rows direct from global: lane c = key row -> coalesced 2KB/wave-load
    const ushort_t* kB = kb + (size_t)bh * (N_ * D_) + (size_t)c * D_ + hh * 8;

    __syncthreads();

    f32x16 oacc = {};
    float sum = 0.f;

    #pragma unroll
    for (int kt = 0; kt < 11; ++kt) {
        // QK^T: A = K rows from global (lane c = key m), k = d
        const ushort_t* krow = kB + kt * 32 * D_;
        short8 ka  = *(const short8*)(krow);        // d = h*8 + j
        short8 kb2 = *(const short8*)(krow + 16);   // d = 16 + h*8 + j
        // C-in = rpb (log2-domain) or -3e38 where masked (replaces zero-init,
        // bias-add and post-exp2 cndmask). reg 4g+i -> m = kt*32+8g+4hh+i.
        unsigned int nibs = dwv[kt] >> (hh * 4);
        f32x16 s;
        #pragma unroll
        for (int g = 0; g < 4; ++g) {
            if (kt == 10 && g == 3) {          // m >= 344: all masked, no load
                s[12] = -3.0e38f; s[13] = -3.0e38f;
                s[14] = -3.0e38f; s[15] = -3.0e38f;
            } else {
                uint2 rv = rp2h[(kt * 8 + 2 * g) * (size_t)N_];
                unsigned int nib = (nibs >> (g * 8)) & 0xFu;
                s[4*g+0] = (nib & 1u) ? b2f(rv.x & 0xffffu) : -3.0e38f;
                s[4*g+1] = (nib & 2u) ? b2f(rv.x >> 16)     : -3.0e38f;
                s[4*g+2] = (nib & 4u) ? b2f(rv.y & 0xffffu) : -3.0e38f;
                s[4*g+3] = (nib & 8u) ? b2f(rv.y >> 16)     : -3.0e38f;
            }
        }
        s = __builtin_amdgcn_mfma_f32_32x32x16_bf16(ka,  qf0, s, 0, 0, 0);
        s = __builtin_amdgcn_mfma_f32_32x32x16_bf16(kb2, qf1, s, 0, 0, 0);

        // exp2 + sum + pack (masked lanes: exp2(-3e38) = exact 0)
        unsigned int pk[8];
        #pragma unroll
        for (int g = 0; g < 4; ++g) {
            float e0 = __builtin_exp2f(s[4*g+0]);
            float e1 = __builtin_exp2f(s[4*g+1]);
            float e2 = __builtin_exp2f(s[4*g+2]);
            float e3 = __builtin_exp2f(s[4*g+3]);
            sum += (e0 + e1) + (e2 + e3);
            pk[2*g]   = cvt_pk(e0, e1);
            pk[2*g+1] = cvt_pk(e2, e3);
        }
        // D-layout -> B-operand layout via half-wave swaps
        pswap(pk[0], pk[2]);
        pswap(pk[1], pk[3]);
        pswap(pk[4], pk[6]);
        pswap(pk[5], pk[7]);
        union { short8 s8; unsigned int u[4]; } pf1, pf2;
        pf1.u[0] = pk[0]; pf1.u[1] = pk[1]; pf1.u[2] = pk[2]; pf1.u[3] = pk[3];
        pf2.u[0] = pk[4]; pf2.u[1] = pk[5]; pf2.u[2] = pk[6]; pf2.u[3] = pk[7];

        // PV: A = V^T rows from LDS (lane c = d), k = m-offset
        const ushort_t* vrow = vls + c * VLS_ + kt * 32 + hh * 8;
        short8 vf1 = *(const short8*)(vrow);
        short8 vf2 = *(const short8*)(vrow + 16);
        oacc = __builtin_amdgcn_mfma_f32_32x32x16_bf16(vf1, pf1.s8, oacc, 0, 0, 0);
        oacc = __builtin_amdgcn_mfma_f32_32x32x16_bf16(vf2, pf2.s8, oacc, 0, 0, 0);
    }

    sum += __shfl_xor(sum, 32);   // halves hold complementary m-subsets

    // store O^T: reg 4g+i -> d = 8g + 4h + i; 4x 8B packed stores
    int n = n0 + c;
    if (n < N_) {
        float inv = 1.0f / sum;
        ushort_t* op = aob + ((size_t)b * N_ + n) * C_ + h * D_ + hh * 4;
        #pragma unroll
        for (int g = 0; g < 4; ++g) {
            uint2 pkk;
            pkk.x = cvt_pk(oacc[4*g+0] * inv, oacc[4*g+1] * inv);
            pkk.y = cvt_pk(oacc[4*g+2] * inv, oacc[4*g+3] * inv);
            *(uint2*)(op + g * 8) = pkk;
        }
    }
}

// ---------------------------------------------------------------------------
extern "C" void kernel_launch(void* const* d_in, const int* in_sizes, int n_in,
                              void* d_out, int out_size, void* d_ws, size_t ws_size,
                              hipStream_t stream)
{
    const float* x_q    = (const float*)d_in[0];
    const float* x_kv   = (const float*)d_in[1];
    const float* mask   = (const float*)d_in[2];
    const float* q_w    = (const float*)d_in[3];
    const float* q_b    = (const float*)d_in[4];
    const float* kv_w   = (const float*)d_in[5];
    const float* kv_b   = (const float*)d_in[6];
    const float* proj_w = (const float*)d_in[7];
    const float* proj_b = (const float*)d_in[8];
    const float* rpb_t  = (const float*)d_in[9];
    const int*   rpi    = (const int*)d_in[10];
    float* out = (float*)d_out;

    // ws: qx 33.7 | kx 33.7 | vtb 34.6 | aob 33.7 | rpbt 1.42 | wb 0.29 | mbt 1.05 MB
    // total 138,522,336 B == round-4 high-water mark (no growth)
    const size_t QKV  = (size_t)B_ * H_ * N_ * D_;       // 16,859,136
    const size_t QKV2 = (size_t)B_ * H_ * D_ * VTS_;     // 17,301,504
    char* ws = (char*)d_ws;
    ushort_t* qx   = (ushort_t*)ws;
    ushort_t* kx   = qx + QKV;
    ushort_t* vtb  = kx + QKV;
    ushort_t* aob  = vtb + QKV2;
    ushort_t* rpbt = aob + QKV;                          // 16B-aligned offset
    ushort_t* wb   = rpbt + (size_t)H_ * RPG_ * N_ * 4;  // 707,952 elems
    unsigned int* mbt = (unsigned int*)(wb + 147456);
    unsigned int* ctr = (unsigned int*)aob;              // dead until attn writes

    wcvt<<<144, 256, 0, stream>>>(q_w, kv_w, proj_w, wb, ctr);
    rpb_gather_b<<<N_, 256, 0, stream>>>(rpb_t, rpi, rpbt);
    mask_bits<<<(NW_ * N_) / 4, 256, 0, stream>>>(mask, mbt);
    vt_pad<<<B_ * H_, 256, 0, stream>>>(vtb);
    gemm_qkv<<<512, 512, 0, stream>>>(
        x_q, x_kv, wb, q_b, kv_b, qx, kx, vtb, ctr);
    attn_mfma<<<4608, 256, 0, stream>>>(qx, kx, vtb, rpbt, mbt, aob);
    gemm_out<<<343, 512, 0, stream>>>(aob, wb, proj_b, out);
}